// Round 1
// baseline (623.997 us; speedup 1.0000x reference)
//
#include <hip/hip_runtime.h>
#include <hip/hip_bf16.h>
#include <stdint.h>

typedef __bf16 bf16x8 __attribute__((ext_vector_type(8)));
typedef float f32x4 __attribute__((ext_vector_type(4)));
typedef unsigned int u32;
typedef __attribute__((address_space(1))) const u32 g_u32;
typedef __attribute__((address_space(3))) u32 l_u32;

__device__ __forceinline__ unsigned short f32_bf16_rne(float f) {
    unsigned u = __float_as_uint(f);
    u += 0x7FFFu + ((u >> 16) & 1u);
    return (unsigned short)(u >> 16);
}

__device__ __forceinline__ void lds16(const void* g, void* l) {
    __builtin_amdgcn_global_load_lds((g_u32*)g, (l_u32*)l, 16, 0, 0);
}

// ---------------- x fp32 -> bf16 (8 elems/thread) ----------------
__global__ void conv_x(const float* __restrict__ x, unsigned short* __restrict__ xb, int n8) {
    int i = blockIdx.x * blockDim.x + threadIdx.x;
    if (i >= n8) return;
    const float4* p = (const float4*)x + (size_t)i * 2;
    float4 a = p[0];
    float4 b = p[1];
    union { unsigned short u[8]; uint4 v; } o;
    o.u[0] = f32_bf16_rne(a.x); o.u[1] = f32_bf16_rne(a.y);
    o.u[2] = f32_bf16_rne(a.z); o.u[3] = f32_bf16_rne(a.w);
    o.u[4] = f32_bf16_rne(b.x); o.u[5] = f32_bf16_rne(b.y);
    o.u[6] = f32_bf16_rne(b.z); o.u[7] = f32_bf16_rne(b.w);
    *((uint4*)xb + i) = o.v;
}

// ------- W[k][n] fp32 -> quantize -> bf16 -> Wt[n][k] (32x32 LDS transpose) -------
__global__ void quant_transpose(const float* __restrict__ W, unsigned short* __restrict__ Wt,
                                const float* __restrict__ kk_p, int K, int N) {
    __shared__ unsigned short tile[32][33];
    const float kk = *kk_p;
    const bool soft = kk < 1000.0f;
    const int kb = blockIdx.y * 32;
    const int nb = blockIdx.x * 32;
    const int tx = threadIdx.x;   // 0..31
    const int ty = threadIdx.y;   // 0..7
    for (int i = ty; i < 32; i += 8) {
        float w = W[(size_t)(kb + i) * N + nb + tx];
        float q = soft ? tanhf(w * kk) : (w > 0.f ? 1.f : (w < 0.f ? -1.f : 0.f));
        tile[i][tx] = f32_bf16_rne(q);
    }
    __syncthreads();
    for (int i = ty; i < 32; i += 8) {
        Wt[(size_t)(nb + i) * K + kb + tx] = tile[tx][i];
    }
}

// ---------------- bf16 GEMM: C = nmk * A(MxK) @ Bt(NxK)^T + bias ----------------
// 128x128 tile, BK=32, 4 waves (2x2), each wave 4x4 tiles of mfma_f32_16x16x32_bf16
__global__ __launch_bounds__(256) void gemm_bf16_bt(
    const unsigned short* __restrict__ A,   // [M][K] bf16
    const unsigned short* __restrict__ Bt,  // [N][K] bf16
    const float* __restrict__ bias,
    const float* __restrict__ nmk_p,
    float* __restrict__ C,
    int M, int N, int K)
{
    __shared__ __align__(16) unsigned short As[128 * 32];
    __shared__ __align__(16) unsigned short Bs[128 * 32];

    const int tid  = threadIdx.x;
    const int wave = tid >> 6;
    const int lane = tid & 63;
    const int mTile = blockIdx.y * 128;
    const int nTile = blockIdx.x * 128;
    const int wm = (wave & 1) * 64;
    const int wn = (wave >> 1) * 64;
    const int lr = lane & 15;          // A-frag row / B-frag col
    const int lk = (lane >> 4) * 8;    // k offset within BK

    f32x4 acc[4][4] = {};

    // staging: thread t loads row t/4 (of 64), cols (t%4)*8..+7; two row-blocks of 64
    const int srow = tid >> 2;
    const int scol = (tid & 3) * 8;
    const unsigned short* Ag0 = A  + (size_t)(mTile + srow) * K + scol;
    const unsigned short* Ag1 = Ag0 + (size_t)64 * K;
    const unsigned short* Bg0 = Bt + (size_t)(nTile + srow) * K + scol;
    const unsigned short* Bg1 = Bg0 + (size_t)64 * K;

    // LDS dest: wave-uniform base + lane*16 (global_load_lds constraint)
    char* asw = (char*)As + wave * 1024;
    char* bsw = (char*)Bs + wave * 1024;

    for (int k0 = 0; k0 < K; k0 += 32) {
        __syncthreads();                      // previous tile's compute done
        lds16(Ag0, asw);
        lds16(Ag1, asw + 4096);
        lds16(Bg0, bsw);
        lds16(Bg1, bsw + 4096);
        Ag0 += 32; Ag1 += 32; Bg0 += 32; Bg1 += 32;
        __syncthreads();                      // barrier drains vmcnt -> LDS valid

        bf16x8 af[4], bf[4];
#pragma unroll
        for (int mi = 0; mi < 4; ++mi)
            af[mi] = *(const bf16x8*)&As[(wm + 16 * mi + lr) * 32 + lk];
#pragma unroll
        for (int ni = 0; ni < 4; ++ni)
            bf[ni] = *(const bf16x8*)&Bs[(wn + 16 * ni + lr) * 32 + lk];
#pragma unroll
        for (int mi = 0; mi < 4; ++mi)
#pragma unroll
            for (int ni = 0; ni < 4; ++ni)
                acc[mi][ni] = __builtin_amdgcn_mfma_f32_16x16x32_bf16(
                    af[mi], bf[ni], acc[mi][ni], 0, 0, 0);
    }

    const float nmk = *nmk_p;
    float bn[4];
#pragma unroll
    for (int ni = 0; ni < 4; ++ni) bn[ni] = bias[nTile + wn + 16 * ni + lr];

    // C/D mapping (verified m89): col = lane&15, row = (lane>>4)*4 + reg
#pragma unroll
    for (int mi = 0; mi < 4; ++mi) {
        const int m0 = mTile + wm + 16 * mi + (lane >> 4) * 4;
#pragma unroll
        for (int ni = 0; ni < 4; ++ni) {
            const int n = nTile + wn + 16 * ni + lr;
            float* cp = C + (size_t)m0 * N + n;
#pragma unroll
            for (int r = 0; r < 4; ++r)
                cp[(size_t)r * N] = nmk * acc[mi][ni][r] + bn[ni];
        }
    }
}

// ---------------- fallback (only if ws too small / odd shapes): fp32 tiled ----------------
__global__ void fallback_gemm(const float* __restrict__ x, const float* __restrict__ W,
                              const float* __restrict__ bias, const float* __restrict__ nmk_p,
                              const float* __restrict__ kk_p, float* __restrict__ C,
                              int M, int N, int K) {
    __shared__ float At[16][17];
    __shared__ float Bq[16][17];
    const int tx = threadIdx.x, ty = threadIdx.y;
    const int n = blockIdx.x * 16 + tx;
    const int m = blockIdx.y * 16 + ty;
    const float kk = *kk_p;
    const bool soft = kk < 1000.f;
    float acc = 0.f;
    for (int k0 = 0; k0 < K; k0 += 16) {
        At[ty][tx] = x[(size_t)m * K + k0 + tx];
        float w = W[(size_t)(k0 + ty) * N + n];
        Bq[ty][tx] = soft ? tanhf(w * kk) : (w > 0.f ? 1.f : (w < 0.f ? -1.f : 0.f));
        __syncthreads();
#pragma unroll
        for (int kk2 = 0; kk2 < 16; ++kk2) acc += At[ty][kk2] * Bq[kk2][tx];
        __syncthreads();
    }
    C[(size_t)m * N + n] = (*nmk_p) * acc + bias[n];
}

extern "C" void kernel_launch(void* const* d_in, const int* in_sizes, int n_in,
                              void* d_out, int out_size, void* d_ws, size_t ws_size,
                              hipStream_t stream) {
    const float* x    = (const float*)d_in[0];
    const float* W    = (const float*)d_in[1];
    const float* bias = (const float*)d_in[2];
    const float* nmk  = (const float*)d_in[3];
    const float* kk   = (const float*)d_in[4];
    float* out = (float*)d_out;

    const int N = in_sizes[2];            // 4096 (bias length)
    const int K = in_sizes[1] / N;        // 4096
    const int M = in_sizes[0] / K;        // 8192

    const size_t need = ((size_t)M * K + (size_t)N * K) * sizeof(unsigned short);
    const bool shapes_ok = (M % 128 == 0) && (N % 128 == 0) && (K % 32 == 0) && (N % 32 == 0);

    if (ws_size >= need && shapes_ok) {
        unsigned short* xb = (unsigned short*)d_ws;         // M*K bf16
        unsigned short* Wt = xb + (size_t)M * K;            // N*K bf16 (transposed W)

        const int n8 = (M * K) / 8;
        conv_x<<<(n8 + 255) / 256, 256, 0, stream>>>(x, xb, n8);

        dim3 qg(N / 32, K / 32);
        quant_transpose<<<qg, dim3(32, 8), 0, stream>>>(W, Wt, kk, K, N);

        dim3 gg(N / 128, M / 128);
        gemm_bf16_bt<<<gg, 256, 0, stream>>>(xb, Wt, bias, nmk, out, M, N, K);
    } else {
        dim3 fg(N / 16, M / 16);
        fallback_gemm<<<fg, dim3(16, 16), 0, stream>>>(x, W, bias, nmk, kk, out, M, N, K);
    }
}

// Round 3
// 605.646 us; speedup vs baseline: 1.0303x; 1.0303x over previous
//
#include <hip/hip_runtime.h>
#include <hip/hip_bf16.h>
#include <stdint.h>

typedef __bf16 bf16x8 __attribute__((ext_vector_type(8)));
typedef float f32x4 __attribute__((ext_vector_type(4)));
typedef unsigned int u32;
typedef __attribute__((address_space(1))) const u32 g_u32;
typedef __attribute__((address_space(3))) u32 l_u32;

__device__ __forceinline__ unsigned short f32_bf16_rne(float f) {
    unsigned u = __float_as_uint(f);
    u += 0x7FFFu + ((u >> 16) & 1u);
    return (unsigned short)(u >> 16);
}

__device__ __forceinline__ void lds16(const void* g, void* l) {
    __builtin_amdgcn_global_load_lds((g_u32*)g, (l_u32*)l, 16, 0, 0);
}

// ---------------- x fp32 -> bf16 (8 elems/thread) ----------------
__global__ void conv_x(const float* __restrict__ x, unsigned short* __restrict__ xb, int n8) {
    int i = blockIdx.x * blockDim.x + threadIdx.x;
    if (i >= n8) return;
    const float4* p = (const float4*)x + (size_t)i * 2;
    float4 a = p[0];
    float4 b = p[1];
    union { unsigned short u[8]; uint4 v; } o;
    o.u[0] = f32_bf16_rne(a.x); o.u[1] = f32_bf16_rne(a.y);
    o.u[2] = f32_bf16_rne(a.z); o.u[3] = f32_bf16_rne(a.w);
    o.u[4] = f32_bf16_rne(b.x); o.u[5] = f32_bf16_rne(b.y);
    o.u[6] = f32_bf16_rne(b.z); o.u[7] = f32_bf16_rne(b.w);
    *((uint4*)xb + i) = o.v;
}

// ------- W[k][n] fp32 -> quantize -> bf16 -> Wt[n][k] -------
// 64x64 tile, 256 threads. float4 loads; transpose via padded LDS (odd word
// stride 33); phase 2: 8 k-elems/thread -> full 64x64 coverage, uint4 stores.
__global__ __launch_bounds__(256) void quant_transpose(
    const float* __restrict__ W, unsigned short* __restrict__ Wt,
    const float* __restrict__ kk_p, int K, int N)
{
    __shared__ unsigned short tileT[64][66];   // [n_local][k_local], 33-word stride
    const float kk = *kk_p;
    const bool soft = kk < 1000.0f;
    const int kb = blockIdx.y * 64;
    const int nb = blockIdx.x * 64;
    const int t = threadIdx.x;

    // Phase 1: 4 iters; thread handles k row r=j*16+(t>>4), 4 n's at c4=(t&15)*4
#pragma unroll
    for (int j = 0; j < 4; ++j) {
        const int r  = j * 16 + (t >> 4);     // k_local
        const int c4 = (t & 15) * 4;          // n_local base
        float4 w = *(const float4*)&W[(size_t)(kb + r) * N + nb + c4];
        float q0, q1, q2, q3;
        if (soft) {
            q0 = tanhf(w.x * kk); q1 = tanhf(w.y * kk);
            q2 = tanhf(w.z * kk); q3 = tanhf(w.w * kk);
        } else {
            q0 = (w.x > 0.f) ? 1.f : (w.x < 0.f ? -1.f : 0.f);
            q1 = (w.y > 0.f) ? 1.f : (w.y < 0.f ? -1.f : 0.f);
            q2 = (w.z > 0.f) ? 1.f : (w.z < 0.f ? -1.f : 0.f);
            q3 = (w.w > 0.f) ? 1.f : (w.w < 0.f ? -1.f : 0.f);
        }
        tileT[c4 + 0][r] = f32_bf16_rne(q0);
        tileT[c4 + 1][r] = f32_bf16_rne(q1);
        tileT[c4 + 2][r] = f32_bf16_rne(q2);
        tileT[c4 + 3][r] = f32_bf16_rne(q3);
    }
    __syncthreads();
    // Phase 2: 2 iters; thread writes 8 k-elems (16B) of Wt row nb+n at chunk c
#pragma unroll
    for (int j = 0; j < 2; ++j) {
        const int n = j * 32 + (t >> 3);
        const int c = (t & 7) * 8;            // k_local base, covers 0..63
        uint4 v;
        v.x = *(const u32*)&tileT[n][c + 0];
        v.y = *(const u32*)&tileT[n][c + 2];
        v.z = *(const u32*)&tileT[n][c + 4];
        v.w = *(const u32*)&tileT[n][c + 6];
        *(uint4*)&Wt[(size_t)(nb + n) * K + kb + c] = v;
    }
}

// ---------------- bf16 GEMM: C = nmk * A(MxK) @ Bt(NxK)^T + bias ----------------
// 128x128 tile, BK=32, 4 waves (2x2), each wave 4x4 mfma_f32_16x16x32_bf16.
// LDS layout XOR-swizzled: 16B chunk c of row r stored at position c ^ ((r>>1)&3)
// -> wave64 ds_read_b128 bank-balanced.
__global__ __launch_bounds__(256) void gemm_bf16_bt(
    const unsigned short* __restrict__ A,   // [M][K] bf16
    const unsigned short* __restrict__ Bt,  // [N][K] bf16
    const float* __restrict__ bias,
    const float* __restrict__ nmk_p,
    float* __restrict__ C,
    int M, int N, int K)
{
    __shared__ __align__(16) unsigned short As[128 * 32];
    __shared__ __align__(16) unsigned short Bs[128 * 32];

    const int tid  = threadIdx.x;
    const int wave = tid >> 6;
    const int lane = tid & 63;
    const int mTile = blockIdx.y * 128;
    const int nTile = blockIdx.x * 128;
    const int wm = (wave & 1) * 64;
    const int wn = (wave >> 1) * 64;
    const int lr = lane & 15;          // A-frag row / B-frag col

    f32x4 acc[4][4] = {};

    // staging: thread t covers row srow=tid>>2; position p=tid&3 holds
    // swizzled source chunk c = p ^ ((srow>>1)&3)
    const int srow = tid >> 2;
    const int scol = (((tid & 3) ^ ((srow >> 1) & 3))) * 8;
    const unsigned short* Ag0 = A  + (size_t)(mTile + srow) * K + scol;
    const unsigned short* Ag1 = Ag0 + (size_t)64 * K;
    const unsigned short* Bg0 = Bt + (size_t)(nTile + srow) * K + scol;
    const unsigned short* Bg1 = Bg0 + (size_t)64 * K;

    // LDS dest: wave-uniform base + lane*16 (global_load_lds constraint)
    char* asw = (char*)As + wave * 1024;
    char* bsw = (char*)Bs + wave * 1024;

    // read-side swizzle: row = wm+16*mi+lr; (row>>1)&3 == (lr>>1)&3 since
    // wm,16*mi are multiples of 16 -> lane-only constant
    const int sw16 = (((lane >> 4) ^ ((lr >> 1) & 3))) * 16;

    for (int k0 = 0; k0 < K; k0 += 32) {
        __syncthreads();                      // previous tile's compute done
        lds16(Ag0, asw);
        lds16(Ag1, asw + 4096);
        lds16(Bg0, bsw);
        lds16(Bg1, bsw + 4096);
        Ag0 += 32; Ag1 += 32; Bg0 += 32; Bg1 += 32;
        __syncthreads();                      // barrier drains vmcnt -> LDS valid

        bf16x8 af[4], bf[4];
#pragma unroll
        for (int mi = 0; mi < 4; ++mi)
            af[mi] = *(const bf16x8*)((const char*)As + (wm + 16 * mi + lr) * 64 + sw16);
#pragma unroll
        for (int ni = 0; ni < 4; ++ni)
            bf[ni] = *(const bf16x8*)((const char*)Bs + (wn + 16 * ni + lr) * 64 + sw16);
#pragma unroll
        for (int mi = 0; mi < 4; ++mi)
#pragma unroll
            for (int ni = 0; ni < 4; ++ni)
                acc[mi][ni] = __builtin_amdgcn_mfma_f32_16x16x32_bf16(
                    af[mi], bf[ni], acc[mi][ni], 0, 0, 0);
    }

    const float nmk = *nmk_p;
    float bn[4];
#pragma unroll
    for (int ni = 0; ni < 4; ++ni) bn[ni] = bias[nTile + wn + 16 * ni + lr];

    // C/D mapping (verified m89): col = lane&15, row = (lane>>4)*4 + reg
#pragma unroll
    for (int mi = 0; mi < 4; ++mi) {
        const int m0 = mTile + wm + 16 * mi + (lane >> 4) * 4;
#pragma unroll
        for (int ni = 0; ni < 4; ++ni) {
            const int n = nTile + wn + 16 * ni + lr;
            float* cp = C + (size_t)m0 * N + n;
#pragma unroll
            for (int r = 0; r < 4; ++r)
                cp[(size_t)r * N] = nmk * acc[mi][ni][r] + bn[ni];
        }
    }
}

// ---------------- fallback (odd shapes / tiny ws): fp32 tiled ----------------
__global__ void fallback_gemm(const float* __restrict__ x, const float* __restrict__ W,
                              const float* __restrict__ bias, const float* __restrict__ nmk_p,
                              const float* __restrict__ kk_p, float* __restrict__ C,
                              int M, int N, int K) {
    __shared__ float At[16][17];
    __shared__ float Bq[16][17];
    const int tx = threadIdx.x, ty = threadIdx.y;
    const int n = blockIdx.x * 16 + tx;
    const int m = blockIdx.y * 16 + ty;
    const float kk = *kk_p;
    const bool soft = kk < 1000.f;
    float acc = 0.f;
    for (int k0 = 0; k0 < K; k0 += 16) {
        At[ty][tx] = x[(size_t)m * K + k0 + tx];
        float w = W[(size_t)(k0 + ty) * N + n];
        Bq[ty][tx] = soft ? tanhf(w * kk) : (w > 0.f ? 1.f : (w < 0.f ? -1.f : 0.f));
        __syncthreads();
#pragma unroll
        for (int kk2 = 0; kk2 < 16; ++kk2) acc += At[ty][kk2] * Bq[kk2][tx];
        __syncthreads();
    }
    C[(size_t)m * N + n] = (*nmk_p) * acc + bias[n];
}

extern "C" void kernel_launch(void* const* d_in, const int* in_sizes, int n_in,
                              void* d_out, int out_size, void* d_ws, size_t ws_size,
                              hipStream_t stream) {
    const float* x    = (const float*)d_in[0];
    const float* W    = (const float*)d_in[1];
    const float* bias = (const float*)d_in[2];
    const float* nmk  = (const float*)d_in[3];
    const float* kk   = (const float*)d_in[4];
    float* out = (float*)d_out;

    const int N = in_sizes[2];            // 4096 (bias length)
    const int K = in_sizes[1] / N;        // 4096
    const int M = in_sizes[0] / K;        // 8192

    const size_t need = ((size_t)M * K + (size_t)N * K) * sizeof(unsigned short);
    const bool shapes_ok = (M % 128 == 0) && (N % 128 == 0) && (K % 64 == 0) &&
                           (N % 64 == 0) && ((M * K) % 2048 == 0);

    if (ws_size >= need && shapes_ok) {
        unsigned short* xb = (unsigned short*)d_ws;         // M*K bf16
        unsigned short* Wt = xb + (size_t)M * K;            // N*K bf16 (W^T, quantized)

        const int n8 = (M * K) / 8;
        conv_x<<<(n8 + 255) / 256, 256, 0, stream>>>(x, xb, n8);

        dim3 qg(N / 64, K / 64);
        quant_transpose<<<qg, 256, 0, stream>>>(W, Wt, kk, K, N);

        dim3 gg(N / 128, M / 128);
        gemm_bf16_bt<<<gg, 256, 0, stream>>>(xb, Wt, bias, nmk, out, M, N, K);
    } else {
        dim3 fg(N / 16, M / 16);
        fallback_gemm<<<fg, dim3(16, 16), 0, stream>>>(x, W, bias, nmk, kk, out, M, N, K);
    }
}

// Round 4
// 588.514 us; speedup vs baseline: 1.0603x; 1.0291x over previous
//
#include <hip/hip_runtime.h>
#include <hip/hip_bf16.h>
#include <stdint.h>

typedef __bf16 bf16x8 __attribute__((ext_vector_type(8)));
typedef float f32x16 __attribute__((ext_vector_type(16)));
typedef unsigned int u32;
typedef __attribute__((address_space(1))) const u32 g_u32;
typedef __attribute__((address_space(3))) u32 l_u32;

__device__ __forceinline__ unsigned short f32_bf16_rne(float f) {
    unsigned u = __float_as_uint(f);
    u += 0x7FFFu + ((u >> 16) & 1u);
    return (unsigned short)(u >> 16);
}

__device__ __forceinline__ float fast_tanh(float z) {
    // 1 - 2/(1+e^{2z}); exact limits at +-inf, error << bf16 quantization
    return 1.0f - 2.0f / (1.0f + __expf(2.0f * z));
}

__device__ __forceinline__ void lds16(const void* g, void* l) {
    __builtin_amdgcn_global_load_lds((g_u32*)g, (l_u32*)l, 16, 0, 0);
}

// ---- fused prep: blocks [0,qblocks) transpose+quantize W; rest convert x ----
__global__ __launch_bounds__(256) void prep(
    const float* __restrict__ x, unsigned short* __restrict__ xb, int n8,
    const float* __restrict__ W, unsigned short* __restrict__ Wt,
    const float* __restrict__ kk_p, int K, int N, int qbx, int qblocks)
{
    const int t = threadIdx.x;
    if ((int)blockIdx.x < qblocks) {
        // ---- W[k][n] -> quant -> Wt[n][k], 64x64 tile ----
        __shared__ unsigned short tileT[64][66];   // [n_local][k_local], 33-word stride
        const float kk = *kk_p;
        const bool soft = kk < 1000.0f;
        const int nb = (blockIdx.x % qbx) * 64;
        const int kb = (blockIdx.x / qbx) * 64;
#pragma unroll
        for (int j = 0; j < 4; ++j) {
            const int r  = j * 16 + (t >> 4);     // k_local
            const int c4 = (t & 15) * 4;          // n_local base
            float4 w = *(const float4*)&W[(size_t)(kb + r) * N + nb + c4];
            float q0, q1, q2, q3;
            if (soft) {
                q0 = fast_tanh(w.x * kk); q1 = fast_tanh(w.y * kk);
                q2 = fast_tanh(w.z * kk); q3 = fast_tanh(w.w * kk);
            } else {
                q0 = (w.x > 0.f) ? 1.f : (w.x < 0.f ? -1.f : 0.f);
                q1 = (w.y > 0.f) ? 1.f : (w.y < 0.f ? -1.f : 0.f);
                q2 = (w.z > 0.f) ? 1.f : (w.z < 0.f ? -1.f : 0.f);
                q3 = (w.w > 0.f) ? 1.f : (w.w < 0.f ? -1.f : 0.f);
            }
            tileT[c4 + 0][r] = f32_bf16_rne(q0);
            tileT[c4 + 1][r] = f32_bf16_rne(q1);
            tileT[c4 + 2][r] = f32_bf16_rne(q2);
            tileT[c4 + 3][r] = f32_bf16_rne(q3);
        }
        __syncthreads();
#pragma unroll
        for (int j = 0; j < 2; ++j) {
            const int n = j * 32 + (t >> 3);
            const int c = (t & 7) * 8;            // covers k_local 0..63
            uint4 v;
            v.x = *(const u32*)&tileT[n][c + 0];
            v.y = *(const u32*)&tileT[n][c + 2];
            v.z = *(const u32*)&tileT[n][c + 4];
            v.w = *(const u32*)&tileT[n][c + 6];
            *(uint4*)&Wt[(size_t)(nb + n) * K + kb + c] = v;
        }
    } else {
        // ---- x fp32 -> bf16, 8 elems/thread ----
        const int i = ((int)blockIdx.x - qblocks) * 256 + t;
        if (i >= n8) return;
        const float4* p = (const float4*)x + (size_t)i * 2;
        float4 a = p[0];
        float4 b = p[1];
        union { unsigned short u[8]; uint4 v; } o;
        o.u[0] = f32_bf16_rne(a.x); o.u[1] = f32_bf16_rne(a.y);
        o.u[2] = f32_bf16_rne(a.z); o.u[3] = f32_bf16_rne(a.w);
        o.u[4] = f32_bf16_rne(b.x); o.u[5] = f32_bf16_rne(b.y);
        o.u[6] = f32_bf16_rne(b.z); o.u[7] = f32_bf16_rne(b.w);
        *((uint4*)xb + i) = o.v;
    }
}

// ---------------- bf16 GEMM: C = nmk * A(MxK) @ Bt(NxK)^T + bias ----------------
// 128x128 tile, BK=32, 4 waves (2x2), each wave 2x2 mfma_f32_32x32x16_bf16.
// A-frag: A[m=lane&31][k=(lane>>5)*8+j] (analogy of verified 16x16x32 layout).
// C/D (HW-verified m74/m101): col=lane&31, row=(reg&3)+8*(reg>>2)+4*(lane>>5).
// LDS XOR-swizzle: 16B chunk c of row r at position c ^ ((r>>1)&3) -> 0 conflicts.
__global__ __launch_bounds__(256) void gemm_bf16_bt(
    const unsigned short* __restrict__ A,   // [M][K] bf16
    const unsigned short* __restrict__ Bt,  // [N][K] bf16
    const float* __restrict__ bias,
    const float* __restrict__ nmk_p,
    float* __restrict__ C,
    int M, int N, int K)
{
    __shared__ __align__(16) unsigned short As[128 * 32];
    __shared__ __align__(16) unsigned short Bs[128 * 32];

    const int tid  = threadIdx.x;
    const int wave = tid >> 6;
    const int lane = tid & 63;
    const int mTile = blockIdx.y * 128;
    const int nTile = blockIdx.x * 128;
    const int wm = (wave & 1) * 64;
    const int wn = (wave >> 1) * 64;
    const int lm = lane & 31;          // frag row (A) / col (B)
    const int half = lane >> 5;        // k 8-chunk selector

    f32x16 acc[2][2] = {};

    // staging: thread t covers row srow=tid>>2; position p=tid&3 holds
    // swizzled source chunk c = p ^ ((srow>>1)&3)
    const int srow = tid >> 2;
    const int scol = (((tid & 3) ^ ((srow >> 1) & 3))) * 8;
    const unsigned short* Ag0 = A  + (size_t)(mTile + srow) * K + scol;
    const unsigned short* Ag1 = Ag0 + (size_t)64 * K;
    const unsigned short* Bg0 = Bt + (size_t)(nTile + srow) * K + scol;
    const unsigned short* Bg1 = Bg0 + (size_t)64 * K;

    // LDS dest: wave-uniform base + lane*16 (global_load_lds constraint)
    char* asw = (char*)As + wave * 1024;
    char* bsw = (char*)Bs + wave * 1024;

    // read swizzle: row = (wm|wn) + 32*mi + lm; (row>>1)&3 == (lane>>1)&3
    const int g = (lane >> 1) & 3;
    const int p0 = (half ^ g) * 16;            // kstep 0 chunk position (bytes)
    // kstep 1 position = (half+2)^g = p0 ^ 32 (bytes)

    for (int k0 = 0; k0 < K; k0 += 32) {
        __syncthreads();                      // previous tile's compute done
        lds16(Ag0, asw);
        lds16(Ag1, asw + 4096);
        lds16(Bg0, bsw);
        lds16(Bg1, bsw + 4096);
        Ag0 += 32; Ag1 += 32; Bg0 += 32; Bg1 += 32;
        __syncthreads();                      // barrier drains vmcnt -> LDS valid

        bf16x8 af[2][2], bf[2][2];
#pragma unroll
        for (int mi = 0; mi < 2; ++mi) {
            const int rb = (wm + 32 * mi + lm) * 64;
            af[mi][0] = *(const bf16x8*)((const char*)As + rb + p0);
            af[mi][1] = *(const bf16x8*)((const char*)As + rb + (p0 ^ 32));
        }
#pragma unroll
        for (int ni = 0; ni < 2; ++ni) {
            const int rb = (wn + 32 * ni + lm) * 64;
            bf[ni][0] = *(const bf16x8*)((const char*)Bs + rb + p0);
            bf[ni][1] = *(const bf16x8*)((const char*)Bs + rb + (p0 ^ 32));
        }
#pragma unroll
        for (int ks = 0; ks < 2; ++ks)
#pragma unroll
            for (int mi = 0; mi < 2; ++mi)
#pragma unroll
                for (int ni = 0; ni < 2; ++ni)
                    acc[mi][ni] = __builtin_amdgcn_mfma_f32_32x32x16_bf16(
                        af[mi][ks], bf[ni][ks], acc[mi][ni], 0, 0, 0);
    }

    const float nmk = *nmk_p;
    float bn[2];
#pragma unroll
    for (int ni = 0; ni < 2; ++ni) bn[ni] = bias[nTile + wn + 32 * ni + lm];

#pragma unroll
    for (int mi = 0; mi < 2; ++mi) {
        const int mbase = mTile + wm + 32 * mi + 4 * half;
#pragma unroll
        for (int ni = 0; ni < 2; ++ni) {
            const int n = nTile + wn + 32 * ni + lm;
#pragma unroll
            for (int reg = 0; reg < 16; ++reg) {
                const int row = mbase + (reg & 3) + 8 * (reg >> 2);
                C[(size_t)row * N + n] = nmk * acc[mi][ni][reg] + bn[ni];
            }
        }
    }
}

// ---------------- fallback (odd shapes / tiny ws): fp32 tiled ----------------
__global__ void fallback_gemm(const float* __restrict__ x, const float* __restrict__ W,
                              const float* __restrict__ bias, const float* __restrict__ nmk_p,
                              const float* __restrict__ kk_p, float* __restrict__ C,
                              int M, int N, int K) {
    __shared__ float At[16][17];
    __shared__ float Bq[16][17];
    const int tx = threadIdx.x, ty = threadIdx.y;
    const int n = blockIdx.x * 16 + tx;
    const int m = blockIdx.y * 16 + ty;
    const float kk = *kk_p;
    const bool soft = kk < 1000.f;
    float acc = 0.f;
    for (int k0 = 0; k0 < K; k0 += 16) {
        At[ty][tx] = x[(size_t)m * K + k0 + tx];
        float w = W[(size_t)(k0 + ty) * N + n];
        Bq[ty][tx] = soft ? tanhf(w * kk) : (w > 0.f ? 1.f : (w < 0.f ? -1.f : 0.f));
        __syncthreads();
#pragma unroll
        for (int kk2 = 0; kk2 < 16; ++kk2) acc += At[ty][kk2] * Bq[kk2][tx];
        __syncthreads();
    }
    C[(size_t)m * N + n] = (*nmk_p) * acc + bias[n];
}

extern "C" void kernel_launch(void* const* d_in, const int* in_sizes, int n_in,
                              void* d_out, int out_size, void* d_ws, size_t ws_size,
                              hipStream_t stream) {
    const float* x    = (const float*)d_in[0];
    const float* W    = (const float*)d_in[1];
    const float* bias = (const float*)d_in[2];
    const float* nmk  = (const float*)d_in[3];
    const float* kk   = (const float*)d_in[4];
    float* out = (float*)d_out;

    const int N = in_sizes[2];            // 4096 (bias length)
    const int K = in_sizes[1] / N;        // 4096
    const int M = in_sizes[0] / K;        // 8192

    const size_t need = ((size_t)M * K + (size_t)N * K) * sizeof(unsigned short);
    const bool shapes_ok = (M % 128 == 0) && (N % 128 == 0) && (K % 64 == 0) &&
                           (N % 64 == 0) && ((M * K) % 2048 == 0);

    if (ws_size >= need && shapes_ok) {
        unsigned short* xb = (unsigned short*)d_ws;         // M*K bf16
        unsigned short* Wt = xb + (size_t)M * K;            // N*K bf16 (W^T, quantized)

        const int n8 = (M * K) / 8;
        const int qbx = N / 64;
        const int qblocks = qbx * (K / 64);
        const int cblocks = (n8 + 255) / 256;
        prep<<<qblocks + cblocks, 256, 0, stream>>>(x, xb, n8, W, Wt, kk, K, N, qbx, qblocks);

        dim3 gg(N / 128, M / 128);
        gemm_bf16_bt<<<gg, 256, 0, stream>>>(xb, Wt, bias, nmk, out, M, N, K);
    } else {
        dim3 fg(N / 16, M / 16);
        fallback_gemm<<<fg, dim3(16, 16), 0, stream>>>(x, W, bias, nmk, kk, out, M, N, K);
    }
}